// Round 2
// baseline (1150.449 us; speedup 1.0000x reference)
//
#include <hip/hip_runtime.h>
#include <math.h>

// SwinBlock on MI355X. Workspace (297.4 MiB total):
//   W(3.54MB bf16 B^T weights) | XW(77.07MB) | Q(77.07) | K(77.07) | V(77.07)
// Aliases: AO=XW (attn out), XN2=Q (LN2 out), H1buf=K+V (154MB, MLP M-halved).
// Residual stream XO lives in d_out (f32): proj writes x+proj there (full
// bijective overwrite -> replay-safe), LN2 reads it, FC2 adds in place.

typedef float f32x4 __attribute__((ext_vector_type(4)));
typedef float f32x2 __attribute__((ext_vector_type(2)));
typedef __bf16 bf16x8 __attribute__((ext_vector_type(8)));
typedef short s16x8 __attribute__((ext_vector_type(8)));
typedef unsigned short u16x2 __attribute__((ext_vector_type(2)));

#define DEV static __device__ __forceinline__

DEV unsigned short f2bf(float f) {
  unsigned int u = __builtin_bit_cast(unsigned int, f);
  u += 0x7fffu + ((u >> 16) & 1u);
  return (unsigned short)(u >> 16);
}
DEV float bf2f(unsigned short h) {
  unsigned int u = ((unsigned int)h) << 16;
  return __builtin_bit_cast(float, u);
}
DEV void load_lds16(const void* g, void* l) {
  __builtin_amdgcn_global_load_lds(
      (const __attribute__((address_space(1))) unsigned int*)g,
      (__attribute__((address_space(3))) unsigned int*)l, 16, 0, 0);
}

// windowed row r (= win*49 + t, shifted coords) -> natural row in x.
DEV int win_src_row(int row) {
  int win = row / 49, t = row - win * 49;
  int bimg = win >> 6, wrem = win & 63;
  int wy = wrem >> 3, wx = wrem & 7;
  int ti = t / 7, tj = t - ti * 7;
  int hh = wy * 7 + ti, ww = wx * 7 + tj;
  int sh = hh + 3; if (sh >= 56) sh -= 56;
  int sw = ww + 3; if (sw >= 56) sw -= 56;
  return bimg * 3136 + sh * 56 + sw;
}

// ---------------- weight cast + transpose: w[K][N] f32 -> wt[N][K] bf16 ----
__global__ void wt_kernel(const float* __restrict__ w, unsigned short* __restrict__ wt,
                          int Kd, int Nd) {
  int idx = blockIdx.x * 256 + threadIdx.x;
  if (idx >= Kd * Nd) return;
  int n = idx / Kd, k = idx - n * Kd;
  wt[idx] = f2bf(w[(size_t)k * Nd + n]);
}

// ---------------- LayerNorm (+ optional shifted-window gather), one wave/row
template <int GATHER>
__global__ __launch_bounds__(256) void ln_kernel(const float* __restrict__ x,
                                                 const float* __restrict__ g,
                                                 const float* __restrict__ bb,
                                                 unsigned short* __restrict__ out) {
  int row = blockIdx.x * 4 + (threadIdx.x >> 6);
  int lane = threadIdx.x & 63;
  int src = GATHER ? win_src_row(row) : row;
  const float* xr = x + (size_t)src * 384;
  f32x2 p0 = *(const f32x2*)(xr + lane * 2);
  f32x2 p1 = *(const f32x2*)(xr + 128 + lane * 2);
  f32x2 p2 = *(const f32x2*)(xr + 256 + lane * 2);
  float s = p0.x + p0.y + p1.x + p1.y + p2.x + p2.y;
  float s2 = p0.x * p0.x + p0.y * p0.y + p1.x * p1.x + p1.y * p1.y +
             p2.x * p2.x + p2.y * p2.y;
#pragma unroll
  for (int off = 32; off; off >>= 1) {
    s += __shfl_xor(s, off);
    s2 += __shfl_xor(s2, off);
  }
  float mu = s * (1.0f / 384.0f);
  float rs = rsqrtf(s2 * (1.0f / 384.0f) - mu * mu + 1e-5f);
  unsigned short* orow = out + (size_t)row * 384;
  int c = lane * 2;
  u16x2 o;
  o.x = f2bf((p0.x - mu) * rs * g[c] + bb[c]);
  o.y = f2bf((p0.y - mu) * rs * g[c + 1] + bb[c + 1]);
  *(u16x2*)(orow + c) = o;
  c += 128;
  o.x = f2bf((p1.x - mu) * rs * g[c] + bb[c]);
  o.y = f2bf((p1.y - mu) * rs * g[c + 1] + bb[c + 1]);
  *(u16x2*)(orow + c) = o;
  c += 128;
  o.x = f2bf((p2.x - mu) * rs * g[c] + bb[c]);
  o.y = f2bf((p2.y - mu) * rs * g[c + 1] + bb[c + 1]);
  *(u16x2*)(orow + c) = o;
}

// ---------------- GEMM: C[M,N] = A[M,K] @ BT[N,K]^T, bf16 in, fused epilogue
// EPI 0: +bqkv, scatter to Q/K/V [win][head][49][32] bf16
// EPI 1: +bproj + x residual, inverse-window scatter, f32 out (d_out as XO)
// EPI 2: +bfc1, exact GELU, bf16 out (H1 chunk)
// EPI 3: +bfc2 + in-place residual on f32 out
template <int EPI>
__global__ __launch_bounds__(256) void gemm_bt(const unsigned short* __restrict__ A,
                                               const unsigned short* __restrict__ BT,
                                               const float* __restrict__ bias, int Kd,
                                               int nTilesN, void* __restrict__ out0,
                                               const float* __restrict__ res) {
  __shared__ __attribute__((aligned(16))) unsigned short As[128 * 32];
  __shared__ __attribute__((aligned(16))) unsigned short Bs[128 * 32];
  const int tid = threadIdx.x;
  const int wid = tid >> 6, lane = tid & 63;
  const int bm = blockIdx.x / nTilesN, bn = blockIdx.x - bm * nTilesN;
  const int wr = wid >> 1, wc = wid & 1;
  f32x4 acc[4][4] = {};
  const int c0 = wid * 2;
  const int srow = lane >> 2;
  const int scol = (lane & 3) << 3;
  const unsigned short* gA0 = A + (size_t)(bm * 128 + c0 * 16 + srow) * Kd + scol;
  const unsigned short* gB0 = BT + (size_t)(bn * 128 + c0 * 16 + srow) * Kd + scol;
  const size_t row16 = (size_t)16 * Kd;
  unsigned short* lA0 = As + c0 * 512;
  unsigned short* lB0 = Bs + c0 * 512;
  const int frow = lane & 15, fk = (lane >> 4) << 3;
  const unsigned short* pa = As + (wr * 64 + frow) * 32 + fk;
  const unsigned short* pb = Bs + (wc * 64 + frow) * 32 + fk;
  for (int k0 = 0; k0 < Kd; k0 += 32) {
    load_lds16(gA0 + k0, lA0);
    load_lds16(gA0 + k0 + row16, lA0 + 512);
    load_lds16(gB0 + k0, lB0);
    load_lds16(gB0 + k0 + row16, lB0 + 512);
    __syncthreads();
    bf16x8 af[4], bfv[4];
#pragma unroll
    for (int m = 0; m < 4; m++) af[m] = *(const bf16x8*)(pa + m * 512);
#pragma unroll
    for (int n = 0; n < 4; n++) bfv[n] = *(const bf16x8*)(pb + n * 512);
#pragma unroll
    for (int m = 0; m < 4; m++)
#pragma unroll
      for (int n = 0; n < 4; n++)
        acc[m][n] = __builtin_amdgcn_mfma_f32_16x16x32_bf16(af[m], bfv[n],
                                                            acc[m][n], 0, 0, 0);
    __syncthreads();
  }
  const int rbase = bm * 128 + wr * 64 + ((lane >> 4) << 2);
  const int cbase = bn * 128 + wc * 64 + (lane & 15);
#pragma unroll
  for (int m = 0; m < 4; m++) {
#pragma unroll
    for (int j = 0; j < 4; j++) {
      const int r = rbase + m * 16 + j;
      if constexpr (EPI == 0) {
        unsigned short* Qb = (unsigned short*)out0;
        int win = r / 49, t = r - win * 49;
        size_t base = (size_t)win * 18816 + (size_t)t * 32;
#pragma unroll
        for (int n = 0; n < 4; n++) {
          int cc = cbase + n * 16;
          float v = acc[m][n][j] + bias[cc];
          int which = cc / 384;
          int rem = cc - which * 384;
          int head = rem >> 5, d = rem & 31;
          Qb[(size_t)which * 38535168 + base + (size_t)head * 1568 + d] = f2bf(v);
        }
      } else if constexpr (EPI == 1) {
        float* XO = (float*)out0;
        size_t srowo = (size_t)win_src_row(r) * 384;
#pragma unroll
        for (int n = 0; n < 4; n++) {
          int cc = cbase + n * 16;
          XO[srowo + cc] = acc[m][n][j] + bias[cc] + res[srowo + cc];
        }
      } else if constexpr (EPI == 2) {
        unsigned short* H1 = (unsigned short*)out0;
        size_t ro = (size_t)r * 1536;
#pragma unroll
        for (int n = 0; n < 4; n++) {
          int cc = cbase + n * 16;
          float u = acc[m][n][j] + bias[cc];
          H1[ro + cc] = f2bf(0.5f * u * (1.0f + erff(u * 0.70710678118654752f)));
        }
      } else {
        float* O = (float*)out0;
        size_t ro = (size_t)r * 384;
#pragma unroll
        for (int n = 0; n < 4; n++) {
          int cc = cbase + n * 16;
          O[ro + cc] = acc[m][n][j] + bias[cc] + res[ro + cc];
        }
      }
    }
  }
}

// ---------------- attention: one wave per (window, head) -------------------
__global__ __launch_bounds__(64) void attn_kernel(const unsigned short* __restrict__ Q,
                                                  const unsigned short* __restrict__ Kb,
                                                  const unsigned short* __restrict__ V,
                                                  unsigned short* __restrict__ AO) {
  __shared__ float Ksf[49 * 32];
  __shared__ float Vsf[49 * 32];
  const int blk = blockIdx.x;
  const int win = blk / 12, head = blk - win * 12;
  const int lane = threadIdx.x;
  const unsigned short* Kp = Kb + (size_t)blk * 1568;
  const unsigned short* Vp = V + (size_t)blk * 1568;
  for (int i = lane; i < 196; i += 64) {
    s16x8 kk = *(const s16x8*)(Kp + i * 8);
    s16x8 vv = *(const s16x8*)(Vp + i * 8);
#pragma unroll
    for (int u = 0; u < 8; u++) {
      Ksf[i * 8 + u] = bf2f((unsigned short)kk[u]);
      Vsf[i * 8 + u] = bf2f((unsigned short)vv[u]);
    }
  }
  __syncthreads();
  float q[32];
  const bool act = lane < 49;
  if (act) {
    const unsigned short* qp = Q + (size_t)blk * 1568 + lane * 32;
#pragma unroll
    for (int u = 0; u < 4; u++) {
      s16x8 qq = *(const s16x8*)(qp + u * 8);
#pragma unroll
      for (int v = 0; v < 8; v++)
        q[u * 8 + v] = bf2f((unsigned short)qq[v]) * 0.17677669529663689f;
    }
  } else {
#pragma unroll
    for (int u = 0; u < 32; u++) q[u] = 0.0f;
  }
  float s[49];
#pragma unroll
  for (int j = 0; j < 49; j++) {
    const f32x4* kr = (const f32x4*)(Ksf + j * 32);
    float d0 = 0, d1 = 0, d2 = 0, d3 = 0;
#pragma unroll
    for (int u = 0; u < 8; u++) {
      f32x4 kv = kr[u];
      d0 += q[u * 4 + 0] * kv.x;
      d1 += q[u * 4 + 1] * kv.y;
      d2 += q[u * 4 + 2] * kv.z;
      d3 += q[u * 4 + 3] * kv.w;
    }
    s[j] = (d0 + d1) + (d2 + d3);
  }
  float mx = s[0];
#pragma unroll
  for (int j = 1; j < 49; j++) mx = fmaxf(mx, s[j]);
  float sum = 0;
#pragma unroll
  for (int j = 0; j < 49; j++) {
    s[j] = __expf(s[j] - mx);
    sum += s[j];
  }
  float inv = 1.0f / sum;
  float o[32];
#pragma unroll
  for (int u = 0; u < 32; u++) o[u] = 0.0f;
#pragma unroll
  for (int j = 0; j < 49; j++) {
    const float p = s[j];
    const f32x4* vr = (const f32x4*)(Vsf + j * 32);
#pragma unroll
    for (int u = 0; u < 8; u++) {
      f32x4 vv = vr[u];
      o[u * 4 + 0] += p * vv.x;
      o[u * 4 + 1] += p * vv.y;
      o[u * 4 + 2] += p * vv.z;
      o[u * 4 + 3] += p * vv.w;
    }
  }
  if (act) {
    unsigned short* op = AO + ((size_t)win * 49 + lane) * 384 + head * 32;
#pragma unroll
    for (int u = 0; u < 4; u++) {
      s16x8 pk;
#pragma unroll
      for (int v = 0; v < 8; v++) pk[v] = (short)f2bf(o[u * 8 + v] * inv);
      *(s16x8*)(op + u * 8) = pk;
    }
  }
}

extern "C" void kernel_launch(void* const* d_in, const int* in_sizes, int n_in,
                              void* d_out, int out_size, void* d_ws, size_t ws_size,
                              hipStream_t stream) {
  (void)in_sizes; (void)n_in; (void)out_size; (void)ws_size;
  const float* x = (const float*)d_in[0];
  const float* g1 = (const float*)d_in[3];
  const float* b1 = (const float*)d_in[4];
  const float* wqkv = (const float*)d_in[5];
  const float* bqkv = (const float*)d_in[6];
  const float* wproj = (const float*)d_in[7];
  const float* bproj = (const float*)d_in[8];
  const float* g2 = (const float*)d_in[9];
  const float* b2 = (const float*)d_in[10];
  const float* wfc1 = (const float*)d_in[11];
  const float* bfc1 = (const float*)d_in[12];
  const float* wfc2 = (const float*)d_in[13];
  const float* bfc2 = (const float*)d_in[14];

  char* ws = (char*)d_ws;
  unsigned short* wqkvT = (unsigned short*)ws;   // [1152][384]
  unsigned short* wprojT = wqkvT + 442368;       // [384][384]
  unsigned short* wfc1T = wprojT + 147456;       // [1536][384]
  unsigned short* wfc2T = wfc1T + 589824;        // [384][1536]
  unsigned short* XW = wfc2T + 589824;           // 100352x384 bf16
  unsigned short* Qb = XW + 38535168;
  unsigned short* Kb = Qb + 38535168;
  unsigned short* Vb = Kb + 38535168;
  // aliases
  unsigned short* AOb = XW;                      // attn out (XW dead)
  unsigned short* XN2 = Qb;                      // LN2 out (Q dead)
  unsigned short* H1buf = Kb;                    // 50176x1536 bf16 (K+V dead)
  float* XO = (float*)d_out;                     // residual stream lives in d_out
  float* out = (float*)d_out;

  wt_kernel<<<1728, 256, 0, stream>>>(wqkv, wqkvT, 384, 1152);
  wt_kernel<<<576, 256, 0, stream>>>(wproj, wprojT, 384, 384);
  wt_kernel<<<2304, 256, 0, stream>>>(wfc1, wfc1T, 384, 1536);
  wt_kernel<<<2304, 256, 0, stream>>>(wfc2, wfc2T, 1536, 384);

  ln_kernel<1><<<25088, 256, 0, stream>>>(x, g1, b1, XW);
  gemm_bt<0><<<784 * 9, 256, 0, stream>>>(XW, wqkvT, bqkv, 384, 9, Qb, nullptr);
  attn_kernel<<<24576, 64, 0, stream>>>(Qb, Kb, Vb, AOb);
  gemm_bt<1><<<784 * 3, 256, 0, stream>>>(AOb, wprojT, bproj, 384, 3, XO, x);
  ln_kernel<0><<<25088, 256, 0, stream>>>(XO, g2, b2, XN2);
  for (int ch = 0; ch < 2; ch++) {
    const unsigned short* a2 = XN2 + (size_t)ch * 50176 * 384;
    float* o2 = out + (size_t)ch * 50176 * 384;
    gemm_bt<2><<<392 * 12, 256, 0, stream>>>(a2, wfc1T, bfc1, 384, 12, H1buf, nullptr);
    gemm_bt<3><<<392 * 3, 256, 0, stream>>>(H1buf, wfc2T, bfc2, 1536, 3, o2, o2);
  }
}

// Round 3
// 1117.054 us; speedup vs baseline: 1.0299x; 1.0299x over previous
//
#include <hip/hip_runtime.h>
#include <math.h>

// SwinBlock on MI355X. Workspace (297.4 MiB total):
//   W(3.54MB bf16 B^T weights) | XW(77.07MB) | Q(77.07) | K(77.07) | V(77.07)
// Aliases: AO=XW (attn out), XN2=Q (LN2 out), H1buf=K+V (154MB, MLP M-halved).
// Residual stream XO lives in d_out (f32).
// R2: GEMM main loop -> 2-phase double-buffered prefetch (STAGE(t+1) issued
// before compute(t), one barrier per K-step). LDS 16->32KB.

typedef float f32x4 __attribute__((ext_vector_type(4)));
typedef float f32x2 __attribute__((ext_vector_type(2)));
typedef __bf16 bf16x8 __attribute__((ext_vector_type(8)));
typedef short s16x8 __attribute__((ext_vector_type(8)));
typedef unsigned short u16x2 __attribute__((ext_vector_type(2)));

#define DEV static __device__ __forceinline__

DEV unsigned short f2bf(float f) {
  unsigned int u = __builtin_bit_cast(unsigned int, f);
  u += 0x7fffu + ((u >> 16) & 1u);
  return (unsigned short)(u >> 16);
}
DEV float bf2f(unsigned short h) {
  unsigned int u = ((unsigned int)h) << 16;
  return __builtin_bit_cast(float, u);
}
DEV void load_lds16(const void* g, void* l) {
  __builtin_amdgcn_global_load_lds(
      (const __attribute__((address_space(1))) unsigned int*)g,
      (__attribute__((address_space(3))) unsigned int*)l, 16, 0, 0);
}

// windowed row r (= win*49 + t, shifted coords) -> natural row in x.
DEV int win_src_row(int row) {
  int win = row / 49, t = row - win * 49;
  int bimg = win >> 6, wrem = win & 63;
  int wy = wrem >> 3, wx = wrem & 7;
  int ti = t / 7, tj = t - ti * 7;
  int hh = wy * 7 + ti, ww = wx * 7 + tj;
  int sh = hh + 3; if (sh >= 56) sh -= 56;
  int sw = ww + 3; if (sw >= 56) sw -= 56;
  return bimg * 3136 + sh * 56 + sw;
}

// ---------------- weight cast + transpose: w[K][N] f32 -> wt[N][K] bf16 ----
__global__ void wt_kernel(const float* __restrict__ w, unsigned short* __restrict__ wt,
                          int Kd, int Nd) {
  int idx = blockIdx.x * 256 + threadIdx.x;
  if (idx >= Kd * Nd) return;
  int n = idx / Kd, k = idx - n * Kd;
  wt[idx] = f2bf(w[(size_t)k * Nd + n]);
}

// ---------------- LayerNorm (+ optional shifted-window gather), one wave/row
template <int GATHER>
__global__ __launch_bounds__(256) void ln_kernel(const float* __restrict__ x,
                                                 const float* __restrict__ g,
                                                 const float* __restrict__ bb,
                                                 unsigned short* __restrict__ out) {
  int row = blockIdx.x * 4 + (threadIdx.x >> 6);
  int lane = threadIdx.x & 63;
  int src = GATHER ? win_src_row(row) : row;
  const float* xr = x + (size_t)src * 384;
  f32x2 p0 = *(const f32x2*)(xr + lane * 2);
  f32x2 p1 = *(const f32x2*)(xr + 128 + lane * 2);
  f32x2 p2 = *(const f32x2*)(xr + 256 + lane * 2);
  float s = p0.x + p0.y + p1.x + p1.y + p2.x + p2.y;
  float s2 = p0.x * p0.x + p0.y * p0.y + p1.x * p1.x + p1.y * p1.y +
             p2.x * p2.x + p2.y * p2.y;
#pragma unroll
  for (int off = 32; off; off >>= 1) {
    s += __shfl_xor(s, off);
    s2 += __shfl_xor(s2, off);
  }
  float mu = s * (1.0f / 384.0f);
  float rs = rsqrtf(s2 * (1.0f / 384.0f) - mu * mu + 1e-5f);
  unsigned short* orow = out + (size_t)row * 384;
  int c = lane * 2;
  u16x2 o;
  o.x = f2bf((p0.x - mu) * rs * g[c] + bb[c]);
  o.y = f2bf((p0.y - mu) * rs * g[c + 1] + bb[c + 1]);
  *(u16x2*)(orow + c) = o;
  c += 128;
  o.x = f2bf((p1.x - mu) * rs * g[c] + bb[c]);
  o.y = f2bf((p1.y - mu) * rs * g[c + 1] + bb[c + 1]);
  *(u16x2*)(orow + c) = o;
  c += 128;
  o.x = f2bf((p2.x - mu) * rs * g[c] + bb[c]);
  o.y = f2bf((p2.y - mu) * rs * g[c + 1] + bb[c + 1]);
  *(u16x2*)(orow + c) = o;
}

// ---------------- GEMM: C[M,N] = A[M,K] @ BT[N,K]^T, bf16 in, fused epilogue
// 2-phase double-buffered: STAGE(buf^1, t+1) issued before compute(t),
// single __syncthreads() per K-step (emits vmcnt(0) lgkmcnt(0) + s_barrier).
// EPI 0: +bqkv, scatter to Q/K/V [win][head][49][32] bf16
// EPI 1: +bproj + x residual, inverse-window scatter, f32 out (d_out as XO)
// EPI 2: +bfc1, exact GELU, bf16 out (H1 chunk)
// EPI 3: +bfc2 + in-place residual on f32 out
template <int EPI>
__global__ __launch_bounds__(256) void gemm_bt(const unsigned short* __restrict__ A,
                                               const unsigned short* __restrict__ BT,
                                               const float* __restrict__ bias, int Kd,
                                               int nTilesN, void* __restrict__ out0,
                                               const float* __restrict__ res) {
  __shared__ __attribute__((aligned(16))) unsigned short As[2][128 * 32];
  __shared__ __attribute__((aligned(16))) unsigned short Bs[2][128 * 32];
  const int tid = threadIdx.x;
  const int wid = tid >> 6, lane = tid & 63;
  const int bm = blockIdx.x / nTilesN, bn = blockIdx.x - bm * nTilesN;
  const int wr = wid >> 1, wc = wid & 1;
  f32x4 acc[4][4] = {};
  // staging: 16 chunks of 1KB per (A,B) tile pair; wave w owns rows [w*32,w*32+32)
  const int c0 = wid * 2;
  const int srow = lane >> 2;
  const int scol = (lane & 3) << 3;
  const unsigned short* gA0 = A + (size_t)(bm * 128 + c0 * 16 + srow) * Kd + scol;
  const unsigned short* gB0 = BT + (size_t)(bn * 128 + c0 * 16 + srow) * Kd + scol;
  const size_t row16 = (size_t)16 * Kd;
  const int lOff = c0 * 512;
  const int frow = lane & 15, fk = (lane >> 4) << 3;
  const int paOff = (wr * 64 + frow) * 32 + fk;
  const int pbOff = (wc * 64 + frow) * 32 + fk;

  auto STAGE = [&](int b, int k0) {
    unsigned short* lA = As[b] + lOff;
    unsigned short* lB = Bs[b] + lOff;
    load_lds16(gA0 + k0, lA);
    load_lds16(gA0 + k0 + row16, lA + 512);
    load_lds16(gB0 + k0, lB);
    load_lds16(gB0 + k0 + row16, lB + 512);
  };

  const int nk = Kd >> 5;
  STAGE(0, 0);
  __syncthreads();
  for (int t = 0; t < nk; ++t) {
    const int b = t & 1;
    if (t + 1 < nk) STAGE(b ^ 1, (t + 1) << 5);
    const unsigned short* pa = As[b] + paOff;
    const unsigned short* pb = Bs[b] + pbOff;
    bf16x8 af[4], bfv[4];
#pragma unroll
    for (int m = 0; m < 4; m++) af[m] = *(const bf16x8*)(pa + m * 512);
#pragma unroll
    for (int n = 0; n < 4; n++) bfv[n] = *(const bf16x8*)(pb + n * 512);
#pragma unroll
    for (int m = 0; m < 4; m++)
#pragma unroll
      for (int n = 0; n < 4; n++)
        acc[m][n] = __builtin_amdgcn_mfma_f32_16x16x32_bf16(af[m], bfv[n],
                                                            acc[m][n], 0, 0, 0);
    __syncthreads();
  }
  const int rbase = bm * 128 + wr * 64 + ((lane >> 4) << 2);
  const int cbase = bn * 128 + wc * 64 + (lane & 15);
#pragma unroll
  for (int m = 0; m < 4; m++) {
#pragma unroll
    for (int j = 0; j < 4; j++) {
      const int r = rbase + m * 16 + j;
      if constexpr (EPI == 0) {
        unsigned short* Qb = (unsigned short*)out0;
        int win = r / 49, t = r - win * 49;
        size_t base = (size_t)win * 18816 + (size_t)t * 32;
#pragma unroll
        for (int n = 0; n < 4; n++) {
          int cc = cbase + n * 16;
          float v = acc[m][n][j] + bias[cc];
          int which = cc / 384;
          int rem = cc - which * 384;
          int head = rem >> 5, d = rem & 31;
          Qb[(size_t)which * 38535168 + base + (size_t)head * 1568 + d] = f2bf(v);
        }
      } else if constexpr (EPI == 1) {
        float* XO = (float*)out0;
        size_t srowo = (size_t)win_src_row(r) * 384;
#pragma unroll
        for (int n = 0; n < 4; n++) {
          int cc = cbase + n * 16;
          XO[srowo + cc] = acc[m][n][j] + bias[cc] + res[srowo + cc];
        }
      } else if constexpr (EPI == 2) {
        unsigned short* H1 = (unsigned short*)out0;
        size_t ro = (size_t)r * 1536;
#pragma unroll
        for (int n = 0; n < 4; n++) {
          int cc = cbase + n * 16;
          float u = acc[m][n][j] + bias[cc];
          H1[ro + cc] = f2bf(0.5f * u * (1.0f + erff(u * 0.70710678118654752f)));
        }
      } else {
        float* O = (float*)out0;
        size_t ro = (size_t)r * 384;
#pragma unroll
        for (int n = 0; n < 4; n++) {
          int cc = cbase + n * 16;
          O[ro + cc] = acc[m][n][j] + bias[cc] + res[ro + cc];
        }
      }
    }
  }
}

// ---------------- attention: one wave per (window, head) -------------------
__global__ __launch_bounds__(64) void attn_kernel(const unsigned short* __restrict__ Q,
                                                  const unsigned short* __restrict__ Kb,
                                                  const unsigned short* __restrict__ V,
                                                  unsigned short* __restrict__ AO) {
  __shared__ float Ksf[49 * 32];
  __shared__ float Vsf[49 * 32];
  const int blk = blockIdx.x;
  const int win = blk / 12, head = blk - win * 12;
  const int lane = threadIdx.x;
  const unsigned short* Kp = Kb + (size_t)blk * 1568;
  const unsigned short* Vp = V + (size_t)blk * 1568;
  for (int i = lane; i < 196; i += 64) {
    s16x8 kk = *(const s16x8*)(Kp + i * 8);
    s16x8 vv = *(const s16x8*)(Vp + i * 8);
#pragma unroll
    for (int u = 0; u < 8; u++) {
      Ksf[i * 8 + u] = bf2f((unsigned short)kk[u]);
      Vsf[i * 8 + u] = bf2f((unsigned short)vv[u]);
    }
  }
  __syncthreads();
  float q[32];
  const bool act = lane < 49;
  if (act) {
    const unsigned short* qp = Q + (size_t)blk * 1568 + lane * 32;
#pragma unroll
    for (int u = 0; u < 4; u++) {
      s16x8 qq = *(const s16x8*)(qp + u * 8);
#pragma unroll
      for (int v = 0; v < 8; v++)
        q[u * 8 + v] = bf2f((unsigned short)qq[v]) * 0.17677669529663689f;
    }
  } else {
#pragma unroll
    for (int u = 0; u < 32; u++) q[u] = 0.0f;
  }
  float s[49];
#pragma unroll
  for (int j = 0; j < 49; j++) {
    const f32x4* kr = (const f32x4*)(Ksf + j * 32);
    float d0 = 0, d1 = 0, d2 = 0, d3 = 0;
#pragma unroll
    for (int u = 0; u < 8; u++) {
      f32x4 kv = kr[u];
      d0 += q[u * 4 + 0] * kv.x;
      d1 += q[u * 4 + 1] * kv.y;
      d2 += q[u * 4 + 2] * kv.z;
      d3 += q[u * 4 + 3] * kv.w;
    }
    s[j] = (d0 + d1) + (d2 + d3);
  }
  float mx = s[0];
#pragma unroll
  for (int j = 1; j < 49; j++) mx = fmaxf(mx, s[j]);
  float sum = 0;
#pragma unroll
  for (int j = 0; j < 49; j++) {
    s[j] = __expf(s[j] - mx);
    sum += s[j];
  }
  float inv = 1.0f / sum;
  float o[32];
#pragma unroll
  for (int u = 0; u < 32; u++) o[u] = 0.0f;
#pragma unroll
  for (int j = 0; j < 49; j++) {
    const float p = s[j];
    const f32x4* vr = (const f32x4*)(Vsf + j * 32);
#pragma unroll
    for (int u = 0; u < 8; u++) {
      f32x4 vv = vr[u];
      o[u * 4 + 0] += p * vv.x;
      o[u * 4 + 1] += p * vv.y;
      o[u * 4 + 2] += p * vv.z;
      o[u * 4 + 3] += p * vv.w;
    }
  }
  if (act) {
    unsigned short* op = AO + ((size_t)win * 49 + lane) * 384 + head * 32;
#pragma unroll
    for (int u = 0; u < 4; u++) {
      s16x8 pk;
#pragma unroll
      for (int v = 0; v < 8; v++) pk[v] = (short)f2bf(o[u * 8 + v] * inv);
      *(s16x8*)(op + u * 8) = pk;
    }
  }
}

extern "C" void kernel_launch(void* const* d_in, const int* in_sizes, int n_in,
                              void* d_out, int out_size, void* d_ws, size_t ws_size,
                              hipStream_t stream) {
  (void)in_sizes; (void)n_in; (void)out_size; (void)ws_size;
  const float* x = (const float*)d_in[0];
  const float* g1 = (const float*)d_in[3];
  const float* b1 = (const float*)d_in[4];
  const float* wqkv = (const float*)d_in[5];
  const float* bqkv = (const float*)d_in[6];
  const float* wproj = (const float*)d_in[7];
  const float* bproj = (const float*)d_in[8];
  const float* g2 = (const float*)d_in[9];
  const float* b2 = (const float*)d_in[10];
  const float* wfc1 = (const float*)d_in[11];
  const float* bfc1 = (const float*)d_in[12];
  const float* wfc2 = (const float*)d_in[13];
  const float* bfc2 = (const float*)d_in[14];

  char* ws = (char*)d_ws;
  unsigned short* wqkvT = (unsigned short*)ws;   // [1152][384]
  unsigned short* wprojT = wqkvT + 442368;       // [384][384]
  unsigned short* wfc1T = wprojT + 147456;       // [1536][384]
  unsigned short* wfc2T = wfc1T + 589824;        // [384][1536]
  unsigned short* XW = wfc2T + 589824;           // 100352x384 bf16
  unsigned short* Qb = XW + 38535168;
  unsigned short* Kb = Qb + 38535168;
  unsigned short* Vb = Kb + 38535168;
  // aliases
  unsigned short* AOb = XW;                      // attn out (XW dead)
  unsigned short* XN2 = Qb;                      // LN2 out (Q dead)
  unsigned short* H1buf = Kb;                    // 50176x1536 bf16 (K+V dead)
  float* XO = (float*)d_out;                     // residual stream lives in d_out
  float* out = (float*)d_out;

  wt_kernel<<<1728, 256, 0, stream>>>(wqkv, wqkvT, 384, 1152);
  wt_kernel<<<576, 256, 0, stream>>>(wproj, wprojT, 384, 384);
  wt_kernel<<<2304, 256, 0, stream>>>(wfc1, wfc1T, 384, 1536);
  wt_kernel<<<2304, 256, 0, stream>>>(wfc2, wfc2T, 1536, 384);

  ln_kernel<1><<<25088, 256, 0, stream>>>(x, g1, b1, XW);
  gemm_bt<0><<<784 * 9, 256, 0, stream>>>(XW, wqkvT, bqkv, 384, 9, Qb, nullptr);
  attn_kernel<<<24576, 64, 0, stream>>>(Qb, Kb, Vb, AOb);
  gemm_bt<1><<<784 * 3, 256, 0, stream>>>(AOb, wprojT, bproj, 384, 3, XO, x);
  ln_kernel<0><<<25088, 256, 0, stream>>>(XO, g2, b2, XN2);
  for (int ch = 0; ch < 2; ch++) {
    const unsigned short* a2 = XN2 + (size_t)ch * 50176 * 384;
    float* o2 = out + (size_t)ch * 50176 * 384;
    gemm_bt<2><<<392 * 12, 256, 0, stream>>>(a2, wfc1T, bfc1, 384, 12, H1buf, nullptr);
    gemm_bt<3><<<392 * 3, 256, 0, stream>>>(H1buf, wfc2T, bfc2, 1536, 3, o2, o2);
  }
}

// Round 4
// 1037.460 us; speedup vs baseline: 1.1089x; 1.0767x over previous
//
#include <hip/hip_runtime.h>
#include <math.h>

// SwinBlock on MI355X. Workspace (297.4 MiB total):
//   W(3.54MB bf16 B^T weights) | XW(77.07MB) | Q(77.07) | K(77.07) | V(77.07)
// Aliases: AO=XW, XN2=Q, H1buf=K+V. Residual stream XO lives in d_out (f32).
// R2: GEMM 2-phase double-buffered prefetch.
// R3: MFMA attention (one wave per (win,head), 16x16x32, swapped-QK softmax);
//     XCD-aware block swizzle on all GEMMs (bijective: all grids % 8 == 0).

typedef float f32x4 __attribute__((ext_vector_type(4)));
typedef float f32x2 __attribute__((ext_vector_type(2)));
typedef __bf16 bf16x8 __attribute__((ext_vector_type(8)));
typedef short s16x8 __attribute__((ext_vector_type(8)));
typedef unsigned short u16x2 __attribute__((ext_vector_type(2)));

#define DEV static __device__ __forceinline__

DEV unsigned short f2bf(float f) {
  unsigned int u = __builtin_bit_cast(unsigned int, f);
  u += 0x7fffu + ((u >> 16) & 1u);
  return (unsigned short)(u >> 16);
}
DEV float bf2f(unsigned short h) {
  unsigned int u = ((unsigned int)h) << 16;
  return __builtin_bit_cast(float, u);
}
DEV void load_lds16(const void* g, void* l) {
  __builtin_amdgcn_global_load_lds(
      (const __attribute__((address_space(1))) unsigned int*)g,
      (__attribute__((address_space(3))) unsigned int*)l, 16, 0, 0);
}

// windowed row r (= win*49 + t, shifted coords) -> natural row in x.
DEV int win_src_row(int row) {
  int win = row / 49, t = row - win * 49;
  int bimg = win >> 6, wrem = win & 63;
  int wy = wrem >> 3, wx = wrem & 7;
  int ti = t / 7, tj = t - ti * 7;
  int hh = wy * 7 + ti, ww = wx * 7 + tj;
  int sh = hh + 3; if (sh >= 56) sh -= 56;
  int sw = ww + 3; if (sw >= 56) sw -= 56;
  return bimg * 3136 + sh * 56 + sw;
}

// ---------------- weight cast + transpose: w[K][N] f32 -> wt[N][K] bf16 ----
__global__ void wt_kernel(const float* __restrict__ w, unsigned short* __restrict__ wt,
                          int Kd, int Nd) {
  int idx = blockIdx.x * 256 + threadIdx.x;
  if (idx >= Kd * Nd) return;
  int n = idx / Kd, k = idx - n * Kd;
  wt[idx] = f2bf(w[(size_t)k * Nd + n]);
}

// ---------------- LayerNorm (+ optional shifted-window gather), one wave/row
template <int GATHER>
__global__ __launch_bounds__(256) void ln_kernel(const float* __restrict__ x,
                                                 const float* __restrict__ g,
                                                 const float* __restrict__ bb,
                                                 unsigned short* __restrict__ out) {
  int row = blockIdx.x * 4 + (threadIdx.x >> 6);
  int lane = threadIdx.x & 63;
  int src = GATHER ? win_src_row(row) : row;
  const float* xr = x + (size_t)src * 384;
  f32x2 p0 = *(const f32x2*)(xr + lane * 2);
  f32x2 p1 = *(const f32x2*)(xr + 128 + lane * 2);
  f32x2 p2 = *(const f32x2*)(xr + 256 + lane * 2);
  float s = p0.x + p0.y + p1.x + p1.y + p2.x + p2.y;
  float s2 = p0.x * p0.x + p0.y * p0.y + p1.x * p1.x + p1.y * p1.y +
             p2.x * p2.x + p2.y * p2.y;
#pragma unroll
  for (int off = 32; off; off >>= 1) {
    s += __shfl_xor(s, off);
    s2 += __shfl_xor(s2, off);
  }
  float mu = s * (1.0f / 384.0f);
  float rs = rsqrtf(s2 * (1.0f / 384.0f) - mu * mu + 1e-5f);
  unsigned short* orow = out + (size_t)row * 384;
  int c = lane * 2;
  u16x2 o;
  o.x = f2bf((p0.x - mu) * rs * g[c] + bb[c]);
  o.y = f2bf((p0.y - mu) * rs * g[c + 1] + bb[c + 1]);
  *(u16x2*)(orow + c) = o;
  c += 128;
  o.x = f2bf((p1.x - mu) * rs * g[c] + bb[c]);
  o.y = f2bf((p1.y - mu) * rs * g[c + 1] + bb[c + 1]);
  *(u16x2*)(orow + c) = o;
  c += 128;
  o.x = f2bf((p2.x - mu) * rs * g[c] + bb[c]);
  o.y = f2bf((p2.y - mu) * rs * g[c + 1] + bb[c + 1]);
  *(u16x2*)(orow + c) = o;
}

// ---------------- GEMM: C[M,N] = A[M,K] @ BT[N,K]^T, bf16 in, fused epilogue
template <int EPI>
__global__ __launch_bounds__(256) void gemm_bt(const unsigned short* __restrict__ A,
                                               const unsigned short* __restrict__ BT,
                                               const float* __restrict__ bias, int Kd,
                                               int nTilesN, void* __restrict__ out0,
                                               const float* __restrict__ res) {
  __shared__ __attribute__((aligned(16))) unsigned short As[2][128 * 32];
  __shared__ __attribute__((aligned(16))) unsigned short Bs[2][128 * 32];
  const int tid = threadIdx.x;
  const int wid = tid >> 6, lane = tid & 63;
  // XCD-aware swizzle: same-XCD blocks get contiguous work ids (A-panel L2 reuse)
  const int nwg = gridDim.x;
  const int swz = (blockIdx.x & 7) * (nwg >> 3) + (blockIdx.x >> 3);
  const int bm = swz / nTilesN, bn = swz - bm * nTilesN;
  const int wr = wid >> 1, wc = wid & 1;
  f32x4 acc[4][4] = {};
  const int c0 = wid * 2;
  const int srow = lane >> 2;
  const int scol = (lane & 3) << 3;
  const unsigned short* gA0 = A + (size_t)(bm * 128 + c0 * 16 + srow) * Kd + scol;
  const unsigned short* gB0 = BT + (size_t)(bn * 128 + c0 * 16 + srow) * Kd + scol;
  const size_t row16 = (size_t)16 * Kd;
  const int lOff = c0 * 512;
  const int frow = lane & 15, fk = (lane >> 4) << 3;
  const int paOff = (wr * 64 + frow) * 32 + fk;
  const int pbOff = (wc * 64 + frow) * 32 + fk;

  auto STAGE = [&](int b, int k0) {
    unsigned short* lA = As[b] + lOff;
    unsigned short* lB = Bs[b] + lOff;
    load_lds16(gA0 + k0, lA);
    load_lds16(gA0 + k0 + row16, lA + 512);
    load_lds16(gB0 + k0, lB);
    load_lds16(gB0 + k0 + row16, lB + 512);
  };

  const int nk = Kd >> 5;
  STAGE(0, 0);
  __syncthreads();
  for (int t = 0; t < nk; ++t) {
    const int b = t & 1;
    if (t + 1 < nk) STAGE(b ^ 1, (t + 1) << 5);
    const unsigned short* pa = As[b] + paOff;
    const unsigned short* pb = Bs[b] + pbOff;
    bf16x8 af[4], bfv[4];
#pragma unroll
    for (int m = 0; m < 4; m++) af[m] = *(const bf16x8*)(pa + m * 512);
#pragma unroll
    for (int n = 0; n < 4; n++) bfv[n] = *(const bf16x8*)(pb + n * 512);
#pragma unroll
    for (int m = 0; m < 4; m++)
#pragma unroll
      for (int n = 0; n < 4; n++)
        acc[m][n] = __builtin_amdgcn_mfma_f32_16x16x32_bf16(af[m], bfv[n],
                                                            acc[m][n], 0, 0, 0);
    __syncthreads();
  }
  const int rbase = bm * 128 + wr * 64 + ((lane >> 4) << 2);
  const int cbase = bn * 128 + wc * 64 + (lane & 15);
#pragma unroll
  for (int m = 0; m < 4; m++) {
#pragma unroll
    for (int j = 0; j < 4; j++) {
      const int r = rbase + m * 16 + j;
      if constexpr (EPI == 0) {
        unsigned short* Qb = (unsigned short*)out0;
        int win = r / 49, t = r - win * 49;
        size_t base = (size_t)win * 18816 + (size_t)t * 32;
#pragma unroll
        for (int n = 0; n < 4; n++) {
          int cc = cbase + n * 16;
          float v = acc[m][n][j] + bias[cc];
          int which = cc / 384;
          int rem = cc - which * 384;
          int head = rem >> 5, d = rem & 31;
          Qb[(size_t)which * 38535168 + base + (size_t)head * 1568 + d] = f2bf(v);
        }
      } else if constexpr (EPI == 1) {
        float* XO = (float*)out0;
        size_t srowo = (size_t)win_src_row(r) * 384;
#pragma unroll
        for (int n = 0; n < 4; n++) {
          int cc = cbase + n * 16;
          XO[srowo + cc] = acc[m][n][j] + bias[cc] + res[srowo + cc];
        }
      } else if constexpr (EPI == 2) {
        unsigned short* H1 = (unsigned short*)out0;
        size_t ro = (size_t)r * 1536;
#pragma unroll
        for (int n = 0; n < 4; n++) {
          int cc = cbase + n * 16;
          float u = acc[m][n][j] + bias[cc];
          H1[ro + cc] = f2bf(0.5f * u * (1.0f + erff(u * 0.70710678118654752f)));
        }
      } else {
        float* O = (float*)out0;
        size_t ro = (size_t)r * 384;
#pragma unroll
        for (int n = 0; n < 4; n++) {
          int cc = cbase + n * 16;
          O[ro + cc] = acc[m][n][j] + bias[cc] + res[ro + cc];
        }
      }
    }
  }
}

// ---------------- MFMA attention: 4 waves/block, one (win,head) per wave ----
// Per wave LDS (u16 elems): Qs[64][32] | Ks[64][32] | VT[32][64] | Ps[16][64]
// S^T = K@Q^T (swapped: softmax over k is lane-local + 2 shfl); P via LDS
// becomes PV's A-fragment; inv-softmax-scale folded into the store.
__global__ __launch_bounds__(256) void attn_mfma(const unsigned short* __restrict__ Q,
                                                 const unsigned short* __restrict__ Kb,
                                                 const unsigned short* __restrict__ V,
                                                 unsigned short* __restrict__ AO) {
  __shared__ __attribute__((aligned(16))) unsigned short L[4][7168];
  const int wid = threadIdx.x >> 6, lane = threadIdx.x & 63;
  const int blk = blockIdx.x * 4 + wid;
  const int win = blk / 12, head = blk - win * 12;
  unsigned short* Qs = L[wid];        // [64][32]
  unsigned short* Ks = Qs + 2048;     // [64][32]
  unsigned short* VT = Qs + 4096;     // [32][64]
  unsigned short* Ps = Qs + 6144;     // [16][64]
  const unsigned short* Qp = Q + (size_t)blk * 1568;
  const unsigned short* Kp = Kb + (size_t)blk * 1568;
  const unsigned short* Vp = V + (size_t)blk * 1568;
  // stage Q,K row-major; V transposed into VT[d][k]
  for (int i = lane; i < 196; i += 64) {
    int row = i >> 2, c8 = (i & 3) << 3;
    *(s16x8*)(Qs + row * 32 + c8) = *(const s16x8*)(Qp + i * 8);
    *(s16x8*)(Ks + row * 32 + c8) = *(const s16x8*)(Kp + i * 8);
    s16x8 vv = *(const s16x8*)(Vp + i * 8);
#pragma unroll
    for (int u = 0; u < 8; u++) VT[(c8 + u) * 64 + row] = (unsigned short)vv[u];
  }
  // zero-pad Q,K rows 49..63 (elements [1568,2048)) and VT cols k in [49,64)
  if (lane < 60) {
    s16x8 z = {};
    *(s16x8*)(Qs + 1568 + lane * 8) = z;
    *(s16x8*)(Ks + 1568 + lane * 8) = z;
  }
  for (int i = lane; i < 480; i += 64) {
    int d = i / 15, k = 49 + (i - d * 15);
    VT[d * 64 + k] = 0;
  }
  __syncthreads();

  const int g = lane >> 4, qi = lane & 15;
  const float scale = 0.17677669529663689f;
  // K A-fragments: constant across q-tiles
  bf16x8 kf[4];
#pragma unroll
  for (int mt = 0; mt < 4; mt++)
    kf[mt] = *(const bf16x8*)(Ks + (mt * 16 + qi) * 32 + g * 8);

  for (int nt = 0; nt < 4; nt++) {
    bf16x8 qf = *(const bf16x8*)(Qs + (nt * 16 + qi) * 32 + g * 8);
    f32x4 st[4];
#pragma unroll
    for (int mt = 0; mt < 4; mt++) {
      f32x4 zz = {};
      st[mt] = __builtin_amdgcn_mfma_f32_16x16x32_bf16(kf[mt], qf, zz, 0, 0, 0);
    }
    // softmax over k for column q=qi+16nt; lane holds k = mt*16 + g*4 + j
    float m = -1e30f;
#pragma unroll
    for (int mt = 0; mt < 3; mt++)
#pragma unroll
      for (int j = 0; j < 4; j++) m = fmaxf(m, st[mt][j]);
    if (g == 0) m = fmaxf(m, st[3][0]);  // k=48
    m = fmaxf(m, __shfl_xor(m, 16));
    m = fmaxf(m, __shfl_xor(m, 32));
    m *= scale;
    float p[4][4];
    float sum = 0.f;
#pragma unroll
    for (int mt = 0; mt < 4; mt++)
#pragma unroll
      for (int j = 0; j < 4; j++) {
        int k = mt * 16 + g * 4 + j;
        float e = (k < 49) ? __expf(st[mt][j] * scale - m) : 0.f;
        p[mt][j] = e;
        sum += e;
      }
    sum += __shfl_xor(sum, 16);
    sum += __shfl_xor(sum, 32);
    float inv = 1.0f / sum;
    // write P (unnormalized) to Ps[q=qi][k], packed pairs
#pragma unroll
    for (int mt = 0; mt < 4; mt++)
#pragma unroll
      for (int j = 0; j < 4; j += 2) {
        unsigned int pk = (unsigned int)f2bf(p[mt][j]) |
                          ((unsigned int)f2bf(p[mt][j + 1]) << 16);
        *(unsigned int*)(Ps + qi * 64 + mt * 16 + g * 4 + j) = pk;
      }
    __syncthreads();
    // PV: out[16 q][32 d] = Ps[16][64] @ V[64][32]
    f32x4 acc0 = {}, acc1 = {};
#pragma unroll
    for (int kt = 0; kt < 2; kt++) {
      bf16x8 pa = *(const bf16x8*)(Ps + qi * 64 + kt * 32 + g * 8);
      bf16x8 vb0 = *(const bf16x8*)(VT + qi * 64 + kt * 32 + g * 8);
      bf16x8 vb1 = *(const bf16x8*)(VT + (16 + qi) * 64 + kt * 32 + g * 8);
      acc0 = __builtin_amdgcn_mfma_f32_16x16x32_bf16(pa, vb0, acc0, 0, 0, 0);
      acc1 = __builtin_amdgcn_mfma_f32_16x16x32_bf16(pa, vb1, acc1, 0, 0, 0);
    }
    // store: C layout row q2=g*4+jr (global q = nt*16+q2), col d = qi (+16)
#pragma unroll
    for (int jr = 0; jr < 4; jr++) {
      int q2 = g * 4 + jr;
      int qg = nt * 16 + q2;
      float iv = __shfl(inv, q2);
      if (qg < 49) {
        unsigned short* op = AO + ((size_t)win * 49 + qg) * 384 + head * 32 + qi;
        op[0] = f2bf(acc0[jr] * iv);
        op[16] = f2bf(acc1[jr] * iv);
      }
    }
    __syncthreads();  // Ps WAR protection before next q-tile
  }
}

extern "C" void kernel_launch(void* const* d_in, const int* in_sizes, int n_in,
                              void* d_out, int out_size, void* d_ws, size_t ws_size,
                              hipStream_t stream) {
  (void)in_sizes; (void)n_in; (void)out_size; (void)ws_size;
  const float* x = (const float*)d_in[0];
  const float* g1 = (const float*)d_in[3];
  const float* b1 = (const float*)d_in[4];
  const float* wqkv = (const float*)d_in[5];
  const float* bqkv = (const float*)d_in[6];
  const float* wproj = (const float*)d_in[7];
  const float* bproj = (const float*)d_in[8];
  const float* g2 = (const float*)d_in[9];
  const float* b2 = (const float*)d_in[10];
  const float* wfc1 = (const float*)d_in[11];
  const float* bfc1 = (const float*)d_in[12];
  const float* wfc2 = (const float*)d_in[13];
  const float* bfc2 = (const float*)d_in[14];

  char* ws = (char*)d_ws;
  unsigned short* wqkvT = (unsigned short*)ws;   // [1152][384]
  unsigned short* wprojT = wqkvT + 442368;       // [384][384]
  unsigned short* wfc1T = wprojT + 147456;       // [1536][384]
  unsigned short* wfc2T = wfc1T + 589824;        // [384][1536]
  unsigned short* XW = wfc2T + 589824;           // 100352x384 bf16
  unsigned short* Qb = XW + 38535168;
  unsigned short* Kb = Qb + 38535168;
  unsigned short* Vb = Kb + 38535168;
  // aliases
  unsigned short* AOb = XW;                      // attn out (XW dead)
  unsigned short* XN2 = Qb;                      // LN2 out (Q dead)
  unsigned short* H1buf = Kb;                    // 50176x1536 bf16 (K+V dead)
  float* XO = (float*)d_out;                     // residual stream lives in d_out
  float* out = (float*)d_out;

  wt_kernel<<<1728, 256, 0, stream>>>(wqkv, wqkvT, 384, 1152);
  wt_kernel<<<576, 256, 0, stream>>>(wproj, wprojT, 384, 384);
  wt_kernel<<<2304, 256, 0, stream>>>(wfc1, wfc1T, 384, 1536);
  wt_kernel<<<2304, 256, 0, stream>>>(wfc2, wfc2T, 1536, 384);

  ln_kernel<1><<<25088, 256, 0, stream>>>(x, g1, b1, XW);
  gemm_bt<0><<<784 * 9, 256, 0, stream>>>(XW, wqkvT, bqkv, 384, 9, Qb, nullptr);
  attn_mfma<<<6144, 256, 0, stream>>>(Qb, Kb, Vb, AOb);
  gemm_bt<1><<<784 * 3, 256, 0, stream>>>(AOb, wprojT, bproj, 384, 3, XO, x);
  ln_kernel<0><<<25088, 256, 0, stream>>>(XO, g2, b2, XN2);
  for (int ch = 0; ch < 2; ch++) {
    const unsigned short* a2 = XN2 + (size_t)ch * 50176 * 384;
    float* o2 = out + (size_t)ch * 50176 * 384;
    gemm_bt<2><<<392 * 12, 256, 0, stream>>>(a2, wfc1T, bfc1, 384, 12, H1buf, nullptr);
    gemm_bt<3><<<392 * 3, 256, 0, stream>>>(H1buf, wfc2T, bfc2, 1536, 3, o2, o2);
  }
}